// Round 3
// baseline (12497.519 us; speedup 1.0000x reference)
//
#include <hip/hip_runtime.h>
#include <hip/hip_cooperative_groups.h>
#include <math.h>

#define NN 4096
#define DD 256
#define NCLS 64
#define EPSF 2.2204460492503131e-16f
#define NITER 64
#define KMAX 64

// ---------------- prep: e = emb/(sigma+eps)/(sigma+eps), sq = rowsum(e*e) ----
__global__ void k_prep(const float* __restrict__ emb, const float* __restrict__ sig,
                       float* __restrict__ e, float* __restrict__ sq) {
  int row = blockIdx.x, t = threadIdx.x;  // block = 256 = DD
  float s = sig[row] + EPSF;
  float v = emb[row * DD + t];
  v = v / s; v = v / s;
  e[row * DD + t] = v;
  __shared__ float red[DD];
  red[t] = v * v; __syncthreads();
  for (int off = 128; off > 0; off >>= 1) {
    if (t < off) red[t] += red[t + off];
    __syncthreads();
  }
  if (t == 0) sq[row] = red[0];
}

// ---------------- dense W = exp(-dist/2), dist = (sq_i+sq_j-2 e.e)/d ---------
#define BK 32
__global__ void k_gemmw(const float* __restrict__ e, const float* __restrict__ sq,
                        float* __restrict__ W) {
  __shared__ float As[64][BK + 1];
  __shared__ float Bs[64][BK + 1];
  int bi = blockIdx.y, bj = blockIdx.x;
  int t = threadIdx.x;               // 256 threads
  int tr = t >> 4, tc = t & 15;      // 16x16, each 4x4 outputs
  int rowbase = bi * 64, colbase = bj * 64;
  float acc[4][4] = {};
  for (int k0 = 0; k0 < DD; k0 += BK) {
    for (int q = t; q < 512; q += 256) {       // 64 rows x 8 quads
      int lr = q >> 3, lq = q & 7;
      float4 a4 = *(const float4*)&e[(size_t)(rowbase + lr) * DD + k0 + lq * 4];
      As[lr][lq * 4 + 0] = a4.x; As[lr][lq * 4 + 1] = a4.y;
      As[lr][lq * 4 + 2] = a4.z; As[lr][lq * 4 + 3] = a4.w;
      float4 b4 = *(const float4*)&e[(size_t)(colbase + lr) * DD + k0 + lq * 4];
      Bs[lr][lq * 4 + 0] = b4.x; Bs[lr][lq * 4 + 1] = b4.y;
      Bs[lr][lq * 4 + 2] = b4.z; Bs[lr][lq * 4 + 3] = b4.w;
    }
    __syncthreads();
    for (int k = 0; k < BK; ++k) {
      float av[4], bv[4];
#pragma unroll
      for (int u = 0; u < 4; ++u) { av[u] = As[tr * 4 + u][k]; bv[u] = Bs[tc * 4 + u][k]; }
#pragma unroll
      for (int u = 0; u < 4; ++u)
#pragma unroll
        for (int v = 0; v < 4; ++v) acc[u][v] += av[u] * bv[v];
    }
    __syncthreads();
  }
#pragma unroll
  for (int u = 0; u < 4; ++u) {
    int i = rowbase + tr * 4 + u;
    float sqi = sq[i];
#pragma unroll
    for (int v = 0; v < 4; ++v) {
      int j = colbase + tc * 4 + v;
      float dist = (sqi + sq[j] - 2.0f * acc[u][v]) * (1.0f / DD);
      W[(size_t)i * NN + j] = expf(-0.5f * dist);
    }
  }
}

// ---------------- zero a u32 buffer ----------------
__global__ void k_zero(unsigned* __restrict__ p, int n) {
  int i = blockIdx.x * blockDim.x + threadIdx.x;
  if (i < n) p[i] = 0u;
}

// ---------------- per-row top-k via repeated argmax (lower index on ties) ----
__global__ void k_topk(const float* __restrict__ W, int* __restrict__ idx,
                       const int* __restrict__ kptr) {
  int row = blockIdx.x, t = threadIdx.x;  // block = 256
  int K = kptr[0]; if (K > KMAX) K = KMAX;
  __shared__ float vals[NN];
  __shared__ float rv[256];
  __shared__ int   ri[256];
  for (int j = t; j < NN; j += 256) vals[j] = W[(size_t)row * NN + j];
  __syncthreads();
  for (int k = 0; k < K; ++k) {
    float best = -1e38f; int bi = NN;
    for (int j = t; j < NN; j += 256) {
      float v = vals[j];
      if (v > best) { best = v; bi = j; }
    }
    rv[t] = best; ri[t] = bi; __syncthreads();
    for (int off = 128; off > 0; off >>= 1) {
      if (t < off) {
        if (rv[t + off] > rv[t] || (rv[t + off] == rv[t] && ri[t + off] < ri[t])) {
          rv[t] = rv[t + off]; ri[t] = ri[t + off];
        }
      }
      __syncthreads();
    }
    if (t == 0) { idx[row * KMAX + k] = ri[0]; vals[ri[0]] = -1e38f; }
    __syncthreads();
  }
}

// ---------------- scatter symmetric bitmask ----------------
__global__ void k_scatter(const int* __restrict__ idx, unsigned* __restrict__ mask,
                          const int* __restrict__ kptr) {
  int K = kptr[0]; if (K > KMAX) K = KMAX;
  int tid = blockIdx.x * blockDim.x + threadIdx.x;
  if (tid >= NN * K) return;
  int i = tid / K, k = tid % K;
  int j = idx[i * KMAX + k];
  atomicOr(&mask[i * 128 + (j >> 5)], 1u << (j & 31));
  atomicOr(&mask[j * 128 + (i >> 5)], 1u << (i & 31));
}

// ---------------- degree (sum of masked W per row) + Dinv + count ------------
__global__ void k_degree(const unsigned* __restrict__ mask, const float* __restrict__ W,
                         float* __restrict__ Dinv, int* __restrict__ deg) {
  int row = blockIdx.x, t = threadIdx.x;  // block = 128 (one 32-bit word each)
  unsigned m = mask[row * 128 + t];
  float dsum = 0.f; int cnt = __popc(m);
  unsigned mm = m;
  while (mm) {
    int b = __ffs(mm) - 1; mm &= mm - 1;
    dsum += W[(size_t)row * NN + t * 32 + b];
  }
  __shared__ float rs[128];
  __shared__ int   rc[128];
  rs[t] = dsum; rc[t] = cnt; __syncthreads();
  for (int off = 64; off > 0; off >>= 1) {
    if (t < off) { rs[t] += rs[t + off]; rc[t] += rc[t + off]; }
    __syncthreads();
  }
  if (t == 0) { deg[row] = rc[0]; Dinv[row] = sqrtf(1.0f / (rs[0] + EPSF)); }
}

// ---------------- exclusive scan of deg -> rowptr (one block) ----------------
__global__ void k_scan(const int* __restrict__ deg, int* __restrict__ rowptr) {
  int t = threadIdx.x;  // 256 threads x 16 rows
  int loc[16]; int s = 0;
  for (int u = 0; u < 16; ++u) { loc[u] = s; s += deg[t * 16 + u]; }
  __shared__ int red[256];
  red[t] = s; __syncthreads();
  int acc = 0;
  for (int u = 0; u < t; ++u) acc += red[u];
  for (int u = 0; u < 16; ++u) rowptr[t * 16 + u] = acc + loc[u];
  if (t == 255) rowptr[NN] = acc + s;
}

// ---------------- fill CSR of alpha*S ----------------
__global__ void k_fill(const unsigned* __restrict__ mask, const float* __restrict__ W,
                       const float* __restrict__ Dinv, const int* __restrict__ rowptr,
                       int* __restrict__ cols, float* __restrict__ vals,
                       const float* __restrict__ alphap) {
  int row = blockIdx.x, t = threadIdx.x;  // block = 128
  float alpha = alphap[0];
  unsigned m = mask[row * 128 + t];
  __shared__ int wcnt[128];
  wcnt[t] = __popc(m); __syncthreads();
  int pre = 0;
  for (int u = 0; u < t; ++u) pre += wcnt[u];
  int base = rowptr[row] + pre;
  float di = Dinv[row];
  while (m) {
    int b = __ffs(m) - 1; m &= m - 1;
    int j = t * 32 + b;
    cols[base] = j;
    vals[base] = alpha * W[(size_t)row * NN + j] * di * Dinv[j];
    ++base;
  }
}

// ---------------- persistent Chebyshev solve: one wave per row, lane=class ---
// X, R, own-D live in registers for all 64 iterations; only neighbor D-rows go
// through global (ping-pong Db0/Db1), with grid.sync() providing the
// device-scope fences needed for cross-XCD visibility.
__global__ __launch_bounds__(256) void k_solve(
    const int* __restrict__ rowptr, const int* __restrict__ cols,
    const float* __restrict__ vals, const int* __restrict__ labels, int Ns,
    const float* __restrict__ alphap, float* __restrict__ Db0,
    float* __restrict__ Db1, float* __restrict__ X) {
  cooperative_groups::grid_group grid = cooperative_groups::this_grid();
  int lane = threadIdx.x & 63;
  int row = (blockIdx.x * 256 + threadIdx.x) >> 6;   // one wave per row
  float alpha = alphap[0];
  float sigma1 = 1.0f / alpha;
  float rho_prev = alpha;
  float b = (row < Ns && labels[row] == lane) ? 1.0f : 0.0f;
  float x = 0.0f, r = b, d = b;
  int p0 = rowptr[row], p1 = rowptr[row + 1];
  size_t o = (size_t)row * 64 + lane;
  Db0[o] = b;
  grid.sync();
  for (int it = 0; it < NITER; ++it) {
    const float* __restrict__ Dc = (it & 1) ? Db1 : Db0;
    float acc0 = 0.f, acc1 = 0.f, acc2 = 0.f, acc3 = 0.f;
    int p = p0;
    for (; p + 3 < p1; p += 4) {
      int   j0 = cols[p],     j1 = cols[p + 1], j2 = cols[p + 2], j3 = cols[p + 3];
      float v0 = vals[p],     v1 = vals[p + 1], v2 = vals[p + 2], v3 = vals[p + 3];
      acc0 += v0 * Dc[(size_t)j0 * 64 + lane];
      acc1 += v1 * Dc[(size_t)j1 * 64 + lane];
      acc2 += v2 * Dc[(size_t)j2 * 64 + lane];
      acc3 += v3 * Dc[(size_t)j3 * 64 + lane];
    }
    for (; p < p1; ++p) acc0 += vals[p] * Dc[(size_t)cols[p] * 64 + lane];
    float s = (acc0 + acc1) + (acc2 + acc3);
    float rho = 1.0f / (2.0f * sigma1 - rho_prev);
    float c1 = rho * rho_prev, c2 = 2.0f * rho / alpha;
    x += d;
    r -= (d - s);          // r -= A d,  A d = d - alpha*S d
    d = c1 * d + c2 * r;
    rho_prev = rho;
    if (it + 1 < NITER) {
      ((it & 1) ? Db0 : Db1)[o] = d;
      grid.sync();
    }
  }
  X[o] = x;
}

// ---------------- host launch ----------------
static inline char* carve(char*& p, size_t bytes) {
  char* r = p;
  size_t a = (bytes + 255) & ~(size_t)255;
  p += a;
  return r;
}

extern "C" void kernel_launch(void* const* d_in, const int* in_sizes, int n_in,
                              void* d_out, int out_size, void* d_ws, size_t ws_size,
                              hipStream_t stream) {
  const float* emb    = (const float*)d_in[0];
  const float* sigma  = (const float*)d_in[1];
  const float* alphap = (const float*)d_in[2];
  const int*   labels = (const int*)d_in[3];
  const int*   kptr   = (const int*)d_in[4];
  int Ns = in_sizes[3];
  float* X = (float*)d_out;   // X state IS the output [NN][64]

  char* p = (char*)d_ws;
  float*    e      = (float*)carve(p, (size_t)NN * DD * 4);
  float*    sq     = (float*)carve(p, NN * 4);
  float*    Wm     = (float*)carve(p, (size_t)NN * NN * 4);
  int*      topk   = (int*)carve(p, NN * KMAX * 4);
  unsigned* mask   = (unsigned*)carve(p, NN * 128 * 4);
  float*    Dinv   = (float*)carve(p, NN * 4);
  int*      deg    = (int*)carve(p, NN * 4);
  int*      rowptr = (int*)carve(p, (NN + 1) * 4);
  int*      cols   = (int*)carve(p, (size_t)NN * 2 * KMAX * 4);
  float*    vals   = (float*)carve(p, (size_t)NN * 2 * KMAX * 4);
  float*    Db0    = (float*)carve(p, (size_t)NN * NCLS * 4);
  float*    Db1    = (float*)carve(p, (size_t)NN * NCLS * 4);

  k_prep<<<NN, DD, 0, stream>>>(emb, sigma, e, sq);
  k_gemmw<<<dim3(NN / 64, NN / 64), 256, 0, stream>>>(e, sq, Wm);
  k_zero<<<(NN * 128 + 255) / 256, 256, 0, stream>>>(mask, NN * 128);
  k_topk<<<NN, 256, 0, stream>>>(Wm, topk, kptr);
  k_scatter<<<(NN * KMAX + 255) / 256, 256, 0, stream>>>(topk, mask, kptr);
  k_degree<<<NN, 128, 0, stream>>>(mask, Wm, Dinv, deg);
  k_scan<<<1, 256, 0, stream>>>(deg, rowptr);
  k_fill<<<NN, 128, 0, stream>>>(mask, Wm, Dinv, rowptr, cols, vals, alphap);

  {
    void* args[] = {
      (void*)&rowptr, (void*)&cols, (void*)&vals, (void*)&labels, (void*)&Ns,
      (void*)&alphap, (void*)&Db0, (void*)&Db1, (void*)&X,
    };
    hipLaunchCooperativeKernel((const void*)k_solve, dim3(NN * NCLS / 256),
                               dim3(256), args, 0, stream);
  }
}

// Round 4
// 1944.018 us; speedup vs baseline: 6.4287x; 6.4287x over previous
//
#include <hip/hip_runtime.h>
#include <math.h>

#define NN 4096
#define DD 256
#define NCLS 64
#define EPSF 2.2204460492503131e-16f
#define NITER 64
#define KMAX 64
#define TASK 32                      // nnz per wave in k_spmm
#define NNZ_CAP (NN * 2 * KMAX)      // static worst case

// ---------------- prep: e = emb/(sigma+eps)/(sigma+eps), sq = rowsum(e*e) ----
__global__ void k_prep(const float* __restrict__ emb, const float* __restrict__ sig,
                       float* __restrict__ e, float* __restrict__ sq) {
  int row = blockIdx.x, t = threadIdx.x;  // block = 256 = DD
  float s = sig[row] + EPSF;
  float v = emb[row * DD + t];
  v = v / s; v = v / s;
  e[row * DD + t] = v;
  __shared__ float red[DD];
  red[t] = v * v; __syncthreads();
  for (int off = 128; off > 0; off >>= 1) {
    if (t < off) red[t] += red[t + off];
    __syncthreads();
  }
  if (t == 0) sq[row] = red[0];
}

// ---------------- dense W = exp(-dist/2), dist = (sq_i+sq_j-2 e.e)/d ---------
#define BK 32
__global__ void k_gemmw(const float* __restrict__ e, const float* __restrict__ sq,
                        float* __restrict__ W) {
  __shared__ float As[64][BK + 1];
  __shared__ float Bs[64][BK + 1];
  int bi = blockIdx.y, bj = blockIdx.x;
  int t = threadIdx.x;               // 256 threads
  int tr = t >> 4, tc = t & 15;      // 16x16, each 4x4 outputs
  int rowbase = bi * 64, colbase = bj * 64;
  float acc[4][4] = {};
  for (int k0 = 0; k0 < DD; k0 += BK) {
    for (int q = t; q < 512; q += 256) {       // 64 rows x 8 quads
      int lr = q >> 3, lq = q & 7;
      float4 a4 = *(const float4*)&e[(size_t)(rowbase + lr) * DD + k0 + lq * 4];
      As[lr][lq * 4 + 0] = a4.x; As[lr][lq * 4 + 1] = a4.y;
      As[lr][lq * 4 + 2] = a4.z; As[lr][lq * 4 + 3] = a4.w;
      float4 b4 = *(const float4*)&e[(size_t)(colbase + lr) * DD + k0 + lq * 4];
      Bs[lr][lq * 4 + 0] = b4.x; Bs[lr][lq * 4 + 1] = b4.y;
      Bs[lr][lq * 4 + 2] = b4.z; Bs[lr][lq * 4 + 3] = b4.w;
    }
    __syncthreads();
    for (int k = 0; k < BK; ++k) {
      float av[4], bv[4];
#pragma unroll
      for (int u = 0; u < 4; ++u) { av[u] = As[tr * 4 + u][k]; bv[u] = Bs[tc * 4 + u][k]; }
#pragma unroll
      for (int u = 0; u < 4; ++u)
#pragma unroll
        for (int v = 0; v < 4; ++v) acc[u][v] += av[u] * bv[v];
    }
    __syncthreads();
  }
#pragma unroll
  for (int u = 0; u < 4; ++u) {
    int i = rowbase + tr * 4 + u;
    float sqi = sq[i];
#pragma unroll
    for (int v = 0; v < 4; ++v) {
      int j = colbase + tc * 4 + v;
      float dist = (sqi + sq[j] - 2.0f * acc[u][v]) * (1.0f / DD);
      W[(size_t)i * NN + j] = expf(-0.5f * dist);
    }
  }
}

// ---------------- zero a u32 buffer ----------------
__global__ void k_zero(unsigned* __restrict__ p, int n) {
  int i = blockIdx.x * blockDim.x + threadIdx.x;
  if (i < n) p[i] = 0u;
}

// ---------------- per-row top-k via repeated argmax (lower index on ties) ----
__global__ void k_topk(const float* __restrict__ W, int* __restrict__ idx,
                       const int* __restrict__ kptr) {
  int row = blockIdx.x, t = threadIdx.x;  // block = 256
  int K = kptr[0]; if (K > KMAX) K = KMAX;
  __shared__ float vals[NN];
  __shared__ float rv[256];
  __shared__ int   ri[256];
  for (int j = t; j < NN; j += 256) vals[j] = W[(size_t)row * NN + j];
  __syncthreads();
  for (int k = 0; k < K; ++k) {
    float best = -1e38f; int bi = NN;
    for (int j = t; j < NN; j += 256) {
      float v = vals[j];
      if (v > best) { best = v; bi = j; }
    }
    rv[t] = best; ri[t] = bi; __syncthreads();
    for (int off = 128; off > 0; off >>= 1) {
      if (t < off) {
        if (rv[t + off] > rv[t] || (rv[t + off] == rv[t] && ri[t + off] < ri[t])) {
          rv[t] = rv[t + off]; ri[t] = ri[t + off];
        }
      }
      __syncthreads();
    }
    if (t == 0) { idx[row * KMAX + k] = ri[0]; vals[ri[0]] = -1e38f; }
    __syncthreads();
  }
}

// ---------------- scatter symmetric bitmask ----------------
__global__ void k_scatter(const int* __restrict__ idx, unsigned* __restrict__ mask,
                          const int* __restrict__ kptr) {
  int K = kptr[0]; if (K > KMAX) K = KMAX;
  int tid = blockIdx.x * blockDim.x + threadIdx.x;
  if (tid >= NN * K) return;
  int i = tid / K, k = tid % K;
  int j = idx[i * KMAX + k];
  atomicOr(&mask[i * 128 + (j >> 5)], 1u << (j & 31));
  atomicOr(&mask[j * 128 + (i >> 5)], 1u << (i & 31));
}

// ---------------- degree (sum of masked W per row) + Dinv + count ------------
__global__ void k_degree(const unsigned* __restrict__ mask, const float* __restrict__ W,
                         float* __restrict__ Dinv, int* __restrict__ deg) {
  int row = blockIdx.x, t = threadIdx.x;  // block = 128 (one 32-bit word each)
  unsigned m = mask[row * 128 + t];
  float dsum = 0.f; int cnt = __popc(m);
  unsigned mm = m;
  while (mm) {
    int b = __ffs(mm) - 1; mm &= mm - 1;
    dsum += W[(size_t)row * NN + t * 32 + b];
  }
  __shared__ float rs[128];
  __shared__ int   rc[128];
  rs[t] = dsum; rc[t] = cnt; __syncthreads();
  for (int off = 64; off > 0; off >>= 1) {
    if (t < off) { rs[t] += rs[t + off]; rc[t] += rc[t + off]; }
    __syncthreads();
  }
  if (t == 0) { deg[row] = rc[0]; Dinv[row] = sqrtf(1.0f / (rs[0] + EPSF)); }
}

// ---------------- exclusive scan of deg -> rowptr (one block) ----------------
__global__ void k_scan(const int* __restrict__ deg, int* __restrict__ rowptr) {
  int t = threadIdx.x;  // 256 threads x 16 rows
  int loc[16]; int s = 0;
  for (int u = 0; u < 16; ++u) { loc[u] = s; s += deg[t * 16 + u]; }
  __shared__ int red[256];
  red[t] = s; __syncthreads();
  int acc = 0;
  for (int u = 0; u < t; ++u) acc += red[u];
  for (int u = 0; u < 16; ++u) rowptr[t * 16 + u] = acc + loc[u];
  if (t == 255) rowptr[NN] = acc + s;
}

// ---------------- fill CSR of alpha*S ----------------
__global__ void k_fill(const unsigned* __restrict__ mask, const float* __restrict__ W,
                       const float* __restrict__ Dinv, const int* __restrict__ rowptr,
                       int* __restrict__ cols, float* __restrict__ vals,
                       const float* __restrict__ alphap) {
  int row = blockIdx.x, t = threadIdx.x;  // block = 128
  float alpha = alphap[0];
  unsigned m = mask[row * 128 + t];
  __shared__ int wcnt[128];
  wcnt[t] = __popc(m); __syncthreads();
  int pre = 0;
  for (int u = 0; u < t; ++u) pre += wcnt[u];
  int base = rowptr[row] + pre;
  float di = Dinv[row];
  while (m) {
    int b = __ffs(m) - 1; m &= m - 1;
    int j = t * 32 + b;
    cols[base] = j;
    vals[base] = alpha * W[(size_t)row * NN + j] * di * Dinv[j];
    ++base;
  }
}

// ---------------- init solver state: X=0, R=D0=B, SV=0 ----------------------
__global__ __launch_bounds__(256) void k_init_state(
    const int* __restrict__ labels, int Ns, float* __restrict__ X,
    float* __restrict__ R, float* __restrict__ D0, float* __restrict__ SV) {
  int idx = blockIdx.x * 256 + threadIdx.x;     // NN*64 total
  int i = idx >> 6, c = idx & 63;
  float b = (i < Ns && labels[i] == c) ? 1.0f : 0.0f;
  X[idx] = 0.0f; R[idx] = b; D0[idx] = b; SV[idx] = 0.0f;
}

// ------- pass 1: SV += (alpha*S) @ D, flat nnz partition, 32 nnz/wave -------
__global__ __launch_bounds__(256) void k_spmm(
    const int* __restrict__ rowptr, const int* __restrict__ cols,
    const float* __restrict__ vals, const float* __restrict__ Dc,
    float* __restrict__ SV) {
  int lane = threadIdx.x & 63;
  int wave = (blockIdx.x * 256 + threadIdx.x) >> 6;
  int nnz = rowptr[NN];
  int start = wave * TASK;
  if (start >= nnz) return;
  int end = start + TASK; if (end > nnz) end = nnz;
  // products: 32 independent gathers, fully unrolled -> deep MLP latency hiding
  float prod[TASK];
#pragma unroll
  for (int u = 0; u < TASK; ++u) {
    int p = start + u;
    if (p < end) prod[u] = vals[p] * Dc[(size_t)cols[p] * 64 + lane];
    else prod[u] = 0.0f;
  }
  // find first row: largest r with rowptr[r] <= start
  int lo = 0, hi = NN;
  while (hi - lo > 1) {
    int mid = (lo + hi) >> 1;
    if (rowptr[mid] <= start) lo = mid; else hi = mid;
  }
  int r = lo;
  int rend = rowptr[r + 1];
  float acc = 0.0f;
#pragma unroll
  for (int u = 0; u < TASK; ++u) {
    int p = start + u;
    if (p >= end) break;
    while (p >= rend) {           // crossed row boundary
      atomicAdd(&SV[(size_t)r * 64 + lane], acc);
      acc = 0.0f; ++r; rend = rowptr[r + 1];
    }
    acc += prod[u];
  }
  atomicAdd(&SV[(size_t)r * 64 + lane], acc);
}

// ------- pass 2: Chebyshev update (streaming), zeroes SV for next iter ------
__global__ __launch_bounds__(256) void k_update(
    float* __restrict__ X, float* __restrict__ R, const float* __restrict__ Dcur,
    float* __restrict__ Dnxt, float* __restrict__ SV,
    const float* __restrict__ alphap, int it) {
  int idx = blockIdx.x * 256 + threadIdx.x;     // NN*64 total
  float alpha = alphap[0];
  float sigma1 = 1.0f / alpha;
  float rho_prev = alpha;
  for (int k = 0; k < it; ++k) rho_prev = 1.0f / (2.0f * sigma1 - rho_prev);
  float rho = 1.0f / (2.0f * sigma1 - rho_prev);
  float c1 = rho * rho_prev, c2 = 2.0f * rho / alpha;
  float s = SV[idx];
  SV[idx] = 0.0f;                  // ready for next iteration's atomics
  float d = Dcur[idx];
  float x = X[idx] + d;
  float r = R[idx] - (d - s);      // r -= A d,  A d = d - alpha*S d
  X[idx] = x; R[idx] = r;
  Dnxt[idx] = c1 * d + c2 * r;
}

// ---------------- host launch ----------------
static inline char* carve(char*& p, size_t bytes) {
  char* r = p;
  size_t a = (bytes + 255) & ~(size_t)255;
  p += a;
  return r;
}

extern "C" void kernel_launch(void* const* d_in, const int* in_sizes, int n_in,
                              void* d_out, int out_size, void* d_ws, size_t ws_size,
                              hipStream_t stream) {
  const float* emb    = (const float*)d_in[0];
  const float* sigma  = (const float*)d_in[1];
  const float* alphap = (const float*)d_in[2];
  const int*   labels = (const int*)d_in[3];
  const int*   kptr   = (const int*)d_in[4];
  int Ns = in_sizes[3];
  float* X = (float*)d_out;   // X state IS the output [NN][64]

  char* p = (char*)d_ws;
  float*    e      = (float*)carve(p, (size_t)NN * DD * 4);
  float*    sq     = (float*)carve(p, NN * 4);
  float*    Wm     = (float*)carve(p, (size_t)NN * NN * 4);
  int*      topk   = (int*)carve(p, NN * KMAX * 4);
  unsigned* mask   = (unsigned*)carve(p, NN * 128 * 4);
  float*    Dinv   = (float*)carve(p, NN * 4);
  int*      deg    = (int*)carve(p, NN * 4);
  int*      rowptr = (int*)carve(p, (NN + 1) * 4);
  int*      cols   = (int*)carve(p, (size_t)NNZ_CAP * 4);
  float*    vals   = (float*)carve(p, (size_t)NNZ_CAP * 4);
  float*    Rbuf   = (float*)carve(p, (size_t)NN * NCLS * 4);
  float*    SV     = (float*)carve(p, (size_t)NN * NCLS * 4);
  float*    Db0    = (float*)carve(p, (size_t)NN * NCLS * 4);
  float*    Db1    = (float*)carve(p, (size_t)NN * NCLS * 4);

  k_prep<<<NN, DD, 0, stream>>>(emb, sigma, e, sq);
  k_gemmw<<<dim3(NN / 64, NN / 64), 256, 0, stream>>>(e, sq, Wm);
  k_zero<<<(NN * 128 + 255) / 256, 256, 0, stream>>>(mask, NN * 128);
  k_topk<<<NN, 256, 0, stream>>>(Wm, topk, kptr);
  k_scatter<<<(NN * KMAX + 255) / 256, 256, 0, stream>>>(topk, mask, kptr);
  k_degree<<<NN, 128, 0, stream>>>(mask, Wm, Dinv, deg);
  k_scan<<<1, 256, 0, stream>>>(deg, rowptr);
  k_fill<<<NN, 128, 0, stream>>>(mask, Wm, Dinv, rowptr, cols, vals, alphap);

  k_init_state<<<(NN * NCLS) / 256, 256, 0, stream>>>(labels, Ns, X, Rbuf, Db0, SV);
  int spmm_blocks = (NNZ_CAP / TASK * 64) / 256;   // waves cover worst-case nnz
  for (int it = 0; it < NITER; ++it) {
    const float* Dc = (it & 1) ? Db1 : Db0;
    float*       Dn = (it & 1) ? Db0 : Db1;
    k_spmm<<<spmm_blocks, 256, 0, stream>>>(rowptr, cols, vals, Dc, SV);
    k_update<<<(NN * NCLS) / 256, 256, 0, stream>>>(X, Rbuf, Dc, Dn, SV, alphap, it);
  }
}